// Round 29
// baseline (118.279 us; speedup 1.0000x reference)
//
#include <hip/hip_runtime.h>
#include <hip/hip_bf16.h>

#define D 128          // D_IN == D_OUT == 128
#define SCAN_CH 4096   // elements per scan block (256 threads x 16)

typedef __bf16 bf16x8 __attribute__((ext_vector_type(8)));
typedef float  f32x4  __attribute__((ext_vector_type(4)));
typedef float  f32x2  __attribute__((ext_vector_type(2)));

__device__ __forceinline__ __bf16 f2bf(float f) { return (__bf16)f; }
__device__ __forceinline__ int pad16(int v) { return (v + 15) & ~15; }

// ---------------------------------------------------------------------------
// Prep (small): zero cnt + pack W into MFMA B-fragment order (bf16).
// ---------------------------------------------------------------------------
__global__ __launch_bounds__(256) void prep_kernel(
    const float* __restrict__ W, __bf16* __restrict__ wb,
    int* __restrict__ cnt, int M)
{
    int t = blockIdx.x * 256 + threadIdx.x;
    for (int i = t; i < M; i += gridDim.x * 256) cnt[i] = 0;

    if (t < 2048) {
        int lane = t & 63;
        int frag = t >> 6;                           // 0..31 = kb*8+fn
        int kb = frag >> 3, fn = frag & 7;
        int n  = fn * 16 + (lane & 15);
        int k0 = kb * 32 + (lane >> 4) * 8;
        const float* src = &W[(size_t)n * D + k0];
        float4 v0 = *reinterpret_cast<const float4*>(src);
        float4 v1 = *reinterpret_cast<const float4*>(src + 4);
        bf16x8 o;
        o[0]=f2bf(v0.x); o[1]=f2bf(v0.y); o[2]=f2bf(v0.z); o[3]=f2bf(v0.w);
        o[4]=f2bf(v1.x); o[5]=f2bf(v1.y); o[6]=f2bf(v1.z); o[7]=f2bf(v1.w);
        *reinterpret_cast<bf16x8*>(&wb[((size_t)frag * 64 + lane) * 8]) = o;
    }
}

// ---------------------------------------------------------------------------
// Parity-interleaved hist || conv (both roles co-resident from t=0):
//   odd blocks:  hist, one edge per thread (rank recorded)  [latency-bound]
//   even blocks: grid-stride x fp32->bf16 + zero bins       [BW-bound]
// ---------------------------------------------------------------------------
__global__ __launch_bounds__(256) void convhist_kernel(
    const float* __restrict__ x, __bf16* __restrict__ xb, long n8,
    int4* __restrict__ bins4, long nbin4,
    const int* __restrict__ dst, int* __restrict__ cnt,
    int* __restrict__ rank, int E, int histBlocks)
{
    const int tid  = threadIdx.x;
    const int half = (int)blockIdx.x >> 1;

    if (blockIdx.x & 1) {
        int e = half * 256 + tid;
        if (e < E) {
            int d = __builtin_nontemporal_load(&dst[e]);
            rank[e] = atomicAdd(&cnt[d], 1);
        }
        return;
    }

    long t    = (long)half * 256 + tid;
    long nthr = (long)histBlocks * 256;
    for (long i = t; i < n8; i += nthr) {
        const f32x4* ap = reinterpret_cast<const f32x4*>(&x[i * 8]);
        f32x4 v0 = ap[0];
        f32x4 v1 = ap[1];
        bf16x8 o;
        o[0]=f2bf(v0[0]); o[1]=f2bf(v0[1]); o[2]=f2bf(v0[2]); o[3]=f2bf(v0[3]);
        o[4]=f2bf(v1[0]); o[5]=f2bf(v1[1]); o[6]=f2bf(v1[2]); o[7]=f2bf(v1[3]);
        *reinterpret_cast<bf16x8*>(&xb[i * 8]) = o;
    }
    for (long i = t; i < nbin4; i += nthr)
        bins4[i] = make_int4(0, 0, 0, 0);
}

// ---------------------------------------------------------------------------
// Two-kernel scan over PADDED counts (pad16); pads pre-zeroed by convhist.
// ---------------------------------------------------------------------------
__global__ __launch_bounds__(256) void scan_part_kernel(
    const int* __restrict__ cnt, int* __restrict__ bsum, int N)
{
    __shared__ int wred[4];
    const int tid  = threadIdx.x;
    const int lane = tid & 63;
    const int wid  = tid >> 6;
    int off = blockIdx.x * SCAN_CH + tid * 16;
    int s = 0;
    #pragma unroll
    for (int i = 0; i < 16; ++i) {
        int idx = off + i;
        if (idx < N) s += pad16(cnt[idx]);
    }
    #pragma unroll
    for (int d = 32; d >= 1; d >>= 1) s += __shfl_xor(s, d, 64);
    if (lane == 0) wred[wid] = s;
    __syncthreads();
    if (tid == 0) bsum[blockIdx.x] = wred[0] + wred[1] + wred[2] + wred[3];
}

__global__ __launch_bounds__(256) void scan_write_kernel(
    const int* __restrict__ cnt, const int* __restrict__ bsum,
    int* __restrict__ base, int N, int NB)
{
    __shared__ int boff_s;
    __shared__ int wsum[4];
    const int b    = blockIdx.x;
    const int tid  = threadIdx.x;
    const int lane = tid & 63;
    const int wid  = tid >> 6;

    if (wid == 0) {
        int v = (lane < b) ? bsum[lane] : 0;   // NB <= 64
        #pragma unroll
        for (int d = 32; d >= 1; d >>= 1) v += __shfl_xor(v, d, 64);
        if (lane == 0) boff_s = v;
    }
    __syncthreads();

    int off = b * SCAN_CH + tid * 16;
    int v[16];
    int s = 0;
    #pragma unroll
    for (int i = 0; i < 16; ++i) {
        int idx = off + i;
        v[i] = (idx < N) ? pad16(cnt[idx]) : 0;
        s += v[i];
    }
    int ssum = s;
    #pragma unroll
    for (int d = 1; d < 64; d <<= 1) {
        int t = __shfl_up(ssum, d, 64);
        if (lane >= d) ssum += t;
    }
    if (lane == 63) wsum[wid] = ssum;
    __syncthreads();
    int woff = 0;
    for (int w = 0; w < wid; ++w) woff += wsum[w];

    int run = boff_s + woff + ssum - s;
    #pragma unroll
    for (int i = 0; i < 16; ++i) {
        int idx = off + i;
        if (idx < N) base[idx] = run;
        if (idx == N - 1) base[N] = run + v[i];   // padded total
        run += v[i];
    }
}

// ---------------------------------------------------------------------------
// Fused bin || GEMM.  GEMM: bf16 A with ALL 8 A-loads HOISTED.
//   blocks [0, gemmBlocks):   GEMM
//   blocks [gemmBlocks, ...): bin (place edges at base[dst]+rank, no atomics)
// ---------------------------------------------------------------------------
__global__ __launch_bounds__(256) void bingemm_kernel(
    const __bf16* __restrict__ xb, const __bf16* __restrict__ wb,
    __bf16* __restrict__ y, int M, int gemmBlocks,
    const int* __restrict__ src, const int* __restrict__ dst,
    const float* __restrict__ ew, const int* __restrict__ base,
    const int* __restrict__ rank, int2* __restrict__ bins, int E)
{
    const int tid = threadIdx.x;

    if ((int)blockIdx.x >= gemmBlocks) {
        int e = ((int)blockIdx.x - gemmBlocks) * 256 + tid;
        if (e < E) {
            int d   = __builtin_nontemporal_load(&dst[e]);
            int sv  = __builtin_nontemporal_load(&src[e]);
            float w = __builtin_nontemporal_load(&ew[e]);
            int rk  = __builtin_nontemporal_load(&rank[e]);
            int p = base[d] + rk;
            bins[p] = make_int2(sv * (D / 2), __float_as_int(w));
        }
        return;
    }

    const int lane = tid & 63;
    const int wv   = tid >> 6;
    const int l15  = lane & 15;
    const int l4   = lane >> 4;
    const int row_base = blockIdx.x * 128 + wv * 32;
    if (row_base >= M) return;

    // ---- hoist ALL A-loads: 2 rows x 4 kb, 8 x bf16x8 = 32 VGPRs ----
    bf16x8 av[2][4];
    #pragma unroll
    for (int mi = 0; mi < 2; ++mi) {
        int row = row_base + mi * 16 + l15;
        int rc  = row < M ? row : M - 1;            // clamp; stores guarded
        const bf16x8* ap = reinterpret_cast<const bf16x8*>(
                               &xb[(size_t)rc * D + l4 * 8]);
        #pragma unroll
        for (int kb = 0; kb < 4; ++kb)
            av[mi][kb] = ap[kb * 4];                // stride 32 bf16 = 4 chunks
    }

    f32x4 acc[2][8];
    #pragma unroll
    for (int mi = 0; mi < 2; ++mi)
        #pragma unroll
        for (int fn = 0; fn < 8; ++fn)
            #pragma unroll
            for (int c = 0; c < 4; ++c) acc[mi][fn][c] = 0.f;

    #pragma unroll
    for (int kb = 0; kb < 4; ++kb) {
        bf16x8 b[8];
        #pragma unroll
        for (int fn = 0; fn < 8; ++fn)
            b[fn] = *reinterpret_cast<const bf16x8*>(
                        &wb[((size_t)(kb * 8 + fn) * 64 + lane) * 8]);
        #pragma unroll
        for (int mi = 0; mi < 2; ++mi) {
            #pragma unroll
            for (int fn = 0; fn < 8; ++fn)
                acc[mi][fn] = __builtin_amdgcn_mfma_f32_16x16x32_bf16(
                                  av[mi][kb], b[fn], acc[mi][fn], 0, 0, 0);
        }
    }

    // C/D layout: col = lane&15 (+fn*16), row = (lane>>4)*4 + r (+mi*16)
    #pragma unroll
    for (int mi = 0; mi < 2; ++mi)
        #pragma unroll
        for (int r = 0; r < 4; ++r) {
            int row = row_base + mi * 16 + l4 * 4 + r;
            if (row >= M) continue;
            #pragma unroll
            for (int fn = 0; fn < 8; ++fn)
                y[(size_t)row * D + fn * 16 + l15] = f2bf(acc[mi][fn][r]);
        }
}

// ---------------------------------------------------------------------------
// Gather-sum from bf16 y: one wave per node, 16 edges in flight, NO bounds
// logic (buckets padded to x16 with {0, 0.0f} entries) -> ~99% of nodes
// complete in a single iteration; 16 y-row loads outstanding per wave.
// ---------------------------------------------------------------------------
__global__ __launch_bounds__(256) void gather_kernel(
    const __bf16* __restrict__ y, const int* __restrict__ base,
    const int2* __restrict__ bins, const float* __restrict__ bias,
    float* __restrict__ out, int N)
{
    int gw   = (blockIdx.x * 256 + threadIdx.x) >> 6;
    int lane = threadIdx.x & 63;
    if (gw >= N) return;

    const unsigned* yb = reinterpret_cast<const unsigned*>(y);  // 2 bf16 / uint
    const int b0 = __builtin_amdgcn_readfirstlane(base[gw]);
    const int b1 = __builtin_amdgcn_readfirstlane(base[gw + 1]);
    float accx = 0.f, accy = 0.f;

    for (int i = b0; i < b1; i += 16) {
        int2 e[16];
        #pragma unroll
        for (int t = 0; t < 16; ++t) e[t] = bins[i + t];
        unsigned p[16];
        #pragma unroll
        for (int t = 0; t < 16; ++t)
            p[t] = yb[(unsigned)e[t].x + lane];
        #pragma unroll
        for (int t = 0; t < 16; ++t) {
            float w = __int_as_float(e[t].y);
            accx += __uint_as_float(p[t] << 16) * w;
            accy += __uint_as_float(p[t] & 0xFFFF0000u) * w;
        }
    }

    float2 bv = *reinterpret_cast<const float2*>(&bias[lane * 2]);
    f32x2 o;
    o[0] = accx + bv.x;
    o[1] = accy + bv.y;
    __builtin_nontemporal_store(o, reinterpret_cast<f32x2*>(&out[(size_t)gw * D + lane * 2]));
}

extern "C" void kernel_launch(void* const* d_in, const int* in_sizes, int n_in,
                              void* d_out, int out_size, void* d_ws, size_t ws_size,
                              hipStream_t stream) {
    const float* x   = (const float*)d_in[0];
    const float* ew  = (const float*)d_in[1];
    const int*   src = (const int*)d_in[2];
    const int*   dst = (const int*)d_in[3];
    const float* W   = (const float*)d_in[4];
    const float* b   = (const float*)d_in[5];
    float*       out = (float*)d_out;

    const int E  = in_sizes[2];                 // 640000
    const int M  = out_size / D;                // 100000 nodes
    const int NB = (M + SCAN_CH - 1) / SCAN_CH; // 25 (<=64 required)
    const size_t BIN_CAP = ((size_t)E + 15 * (size_t)M + 16) & ~(size_t)1;
    const long   N8      = (long)M * D / 8;     // 1.6M bf16x8 chunks

    // ws layout: y bf16[M*D] | xb bf16[M*D] | wb bf16[32*64*8] |
    //            bins int2[BIN_CAP] | base[M+1] | cnt[M] | rank[E] | bsum[NB]
    char* p = (char*)d_ws;
    __bf16* y    = (__bf16*)p;             p += (size_t)M * D * 2;
    __bf16* xb   = (__bf16*)p;             p += (size_t)M * D * 2;
    __bf16* wb   = (__bf16*)p;             p += (size_t)32 * 64 * 8 * 2;
    int2*   bins = (int2*)p;               p += BIN_CAP * 8;
    int*    base = (int*)p;                p += (size_t)(M + 1) * 4;
    int*    cnt  = (int*)p;                p += (size_t)M * 4;
    int*    rank = (int*)p;                p += (size_t)E * 4;
    int*    bsum = (int*)p;

    // 1) zero cnt + pack W (small)
    prep_kernel<<<512, 256, 0, stream>>>(W, wb, cnt, M);

    // 2) parity-interleaved: hist (odd blocks) || conv+zero-bins (even blocks)
    int histBlocks = (E + 255) / 256;           // 2500
    convhist_kernel<<<2 * histBlocks, 256, 0, stream>>>(
        x, xb, N8, (int4*)bins, (long)(BIN_CAP / 2), dst, cnt, rank, E, histBlocks);

    // 3-4) scan over padded counts (pad16)
    scan_part_kernel<<<NB, 256, 0, stream>>>(cnt, bsum, M);
    scan_write_kernel<<<NB, 256, 0, stream>>>(cnt, bsum, base, M, NB);

    // 5) fused: bf16-A GEMM (hoisted A-loads) blocks first, bin blocks trail
    int gemmBlocks = (M + 127) / 128;           // 782
    int binBlocks  = (E + 255) / 256;           // 2500
    bingemm_kernel<<<gemmBlocks + binBlocks, 256, 0, stream>>>(
        xb, wb, y, M, gemmBlocks, src, dst, ew, base, rank, bins, E);

    // 6) out[n] = sum_{e in node n} y[src_e] * w_e + bias  (16-deep MLP)
    gather_kernel<<<(M * 64 + 255) / 256, 256, 0, stream>>>(y, base, bins, b, out, M);
}

// Round 30
// 114.878 us; speedup vs baseline: 1.0296x; 1.0296x over previous
//
#include <hip/hip_runtime.h>
#include <hip/hip_bf16.h>

#define D 128          // D_IN == D_OUT == 128
#define SCAN_CH 4096   // elements per scan block (256 threads x 16)

typedef __bf16 bf16x8 __attribute__((ext_vector_type(8)));
typedef float  f32x4  __attribute__((ext_vector_type(4)));
typedef float  f32x2  __attribute__((ext_vector_type(2)));

__device__ __forceinline__ __bf16 f2bf(float f) { return (__bf16)f; }
__device__ __forceinline__ int pad8(int v) { return (v + 7) & ~7; }

// ---------------------------------------------------------------------------
// Prep (small): zero cnt + pack W into MFMA B-fragment order (bf16).
// ---------------------------------------------------------------------------
__global__ __launch_bounds__(256) void prep_kernel(
    const float* __restrict__ W, __bf16* __restrict__ wb,
    int* __restrict__ cnt, int M)
{
    int t = blockIdx.x * 256 + threadIdx.x;
    for (int i = t; i < M; i += gridDim.x * 256) cnt[i] = 0;

    if (t < 2048) {
        int lane = t & 63;
        int frag = t >> 6;                           // 0..31 = kb*8+fn
        int kb = frag >> 3, fn = frag & 7;
        int n  = fn * 16 + (lane & 15);
        int k0 = kb * 32 + (lane >> 4) * 8;
        const float* src = &W[(size_t)n * D + k0];
        float4 v0 = *reinterpret_cast<const float4*>(src);
        float4 v1 = *reinterpret_cast<const float4*>(src + 4);
        bf16x8 o;
        o[0]=f2bf(v0.x); o[1]=f2bf(v0.y); o[2]=f2bf(v0.z); o[3]=f2bf(v0.w);
        o[4]=f2bf(v1.x); o[5]=f2bf(v1.y); o[6]=f2bf(v1.z); o[7]=f2bf(v1.w);
        *reinterpret_cast<bf16x8*>(&wb[((size_t)frag * 64 + lane) * 8]) = o;
    }
}

// ---------------------------------------------------------------------------
// Parity-interleaved hist || conv (both roles co-resident from t=0):
//   odd blocks:  hist, one edge per thread (rank recorded)  [latency-bound]
//   even blocks: grid-stride x fp32->bf16 + zero bins       [BW-bound]
// ---------------------------------------------------------------------------
__global__ __launch_bounds__(256) void convhist_kernel(
    const float* __restrict__ x, __bf16* __restrict__ xb, long n8,
    int4* __restrict__ bins4, long nbin4,
    const int* __restrict__ dst, int* __restrict__ cnt,
    int* __restrict__ rank, int E, int histBlocks)
{
    const int tid  = threadIdx.x;
    const int half = (int)blockIdx.x >> 1;

    if (blockIdx.x & 1) {
        int e = half * 256 + tid;
        if (e < E) {
            int d = __builtin_nontemporal_load(&dst[e]);
            rank[e] = atomicAdd(&cnt[d], 1);
        }
        return;
    }

    long t    = (long)half * 256 + tid;
    long nthr = (long)histBlocks * 256;
    for (long i = t; i < n8; i += nthr) {
        const f32x4* ap = reinterpret_cast<const f32x4*>(&x[i * 8]);
        f32x4 v0 = ap[0];
        f32x4 v1 = ap[1];
        bf16x8 o;
        o[0]=f2bf(v0[0]); o[1]=f2bf(v0[1]); o[2]=f2bf(v0[2]); o[3]=f2bf(v0[3]);
        o[4]=f2bf(v1[0]); o[5]=f2bf(v1[1]); o[6]=f2bf(v1[2]); o[7]=f2bf(v1[3]);
        *reinterpret_cast<bf16x8*>(&xb[i * 8]) = o;
    }
    for (long i = t; i < nbin4; i += nthr)
        bins4[i] = make_int4(0, 0, 0, 0);
}

// ---------------------------------------------------------------------------
// Two-kernel scan over PADDED counts (pad8); pads pre-zeroed by convhist.
// ---------------------------------------------------------------------------
__global__ __launch_bounds__(256) void scan_part_kernel(
    const int* __restrict__ cnt, int* __restrict__ bsum, int N)
{
    __shared__ int wred[4];
    const int tid  = threadIdx.x;
    const int lane = tid & 63;
    const int wid  = tid >> 6;
    int off = blockIdx.x * SCAN_CH + tid * 16;
    int s = 0;
    #pragma unroll
    for (int i = 0; i < 16; ++i) {
        int idx = off + i;
        if (idx < N) s += pad8(cnt[idx]);
    }
    #pragma unroll
    for (int d = 32; d >= 1; d >>= 1) s += __shfl_xor(s, d, 64);
    if (lane == 0) wred[wid] = s;
    __syncthreads();
    if (tid == 0) bsum[blockIdx.x] = wred[0] + wred[1] + wred[2] + wred[3];
}

__global__ __launch_bounds__(256) void scan_write_kernel(
    const int* __restrict__ cnt, const int* __restrict__ bsum,
    int* __restrict__ base, int N, int NB)
{
    __shared__ int boff_s;
    __shared__ int wsum[4];
    const int b    = blockIdx.x;
    const int tid  = threadIdx.x;
    const int lane = tid & 63;
    const int wid  = tid >> 6;

    if (wid == 0) {
        int v = (lane < b) ? bsum[lane] : 0;   // NB <= 64
        #pragma unroll
        for (int d = 32; d >= 1; d >>= 1) v += __shfl_xor(v, d, 64);
        if (lane == 0) boff_s = v;
    }
    __syncthreads();

    int off = b * SCAN_CH + tid * 16;
    int v[16];
    int s = 0;
    #pragma unroll
    for (int i = 0; i < 16; ++i) {
        int idx = off + i;
        v[i] = (idx < N) ? pad8(cnt[idx]) : 0;
        s += v[i];
    }
    int ssum = s;
    #pragma unroll
    for (int d = 1; d < 64; d <<= 1) {
        int t = __shfl_up(ssum, d, 64);
        if (lane >= d) ssum += t;
    }
    if (lane == 63) wsum[wid] = ssum;
    __syncthreads();
    int woff = 0;
    for (int w = 0; w < wid; ++w) woff += wsum[w];

    int run = boff_s + woff + ssum - s;
    #pragma unroll
    for (int i = 0; i < 16; ++i) {
        int idx = off + i;
        if (idx < N) base[idx] = run;
        if (idx == N - 1) base[N] = run + v[i];   // padded total
        run += v[i];
    }
}

// ---------------------------------------------------------------------------
// Fused bin || GEMM.  GEMM: bf16 A with ALL 8 A-loads HOISTED.
//   blocks [0, gemmBlocks):   GEMM
//   blocks [gemmBlocks, ...): bin (place edges at base[dst]+rank, no atomics)
// ---------------------------------------------------------------------------
__global__ __launch_bounds__(256) void bingemm_kernel(
    const __bf16* __restrict__ xb, const __bf16* __restrict__ wb,
    __bf16* __restrict__ y, int M, int gemmBlocks,
    const int* __restrict__ src, const int* __restrict__ dst,
    const float* __restrict__ ew, const int* __restrict__ base,
    const int* __restrict__ rank, int2* __restrict__ bins, int E)
{
    const int tid = threadIdx.x;

    if ((int)blockIdx.x >= gemmBlocks) {
        int e = ((int)blockIdx.x - gemmBlocks) * 256 + tid;
        if (e < E) {
            int d   = __builtin_nontemporal_load(&dst[e]);
            int sv  = __builtin_nontemporal_load(&src[e]);
            float w = __builtin_nontemporal_load(&ew[e]);
            int rk  = __builtin_nontemporal_load(&rank[e]);
            int p = base[d] + rk;
            bins[p] = make_int2(sv * (D / 2), __float_as_int(w));
        }
        return;
    }

    const int lane = tid & 63;
    const int wv   = tid >> 6;
    const int l15  = lane & 15;
    const int l4   = lane >> 4;
    const int row_base = blockIdx.x * 128 + wv * 32;
    if (row_base >= M) return;

    // ---- hoist ALL A-loads: 2 rows x 4 kb, 8 x bf16x8 = 32 VGPRs ----
    bf16x8 av[2][4];
    #pragma unroll
    for (int mi = 0; mi < 2; ++mi) {
        int row = row_base + mi * 16 + l15;
        int rc  = row < M ? row : M - 1;            // clamp; stores guarded
        const bf16x8* ap = reinterpret_cast<const bf16x8*>(
                               &xb[(size_t)rc * D + l4 * 8]);
        #pragma unroll
        for (int kb = 0; kb < 4; ++kb)
            av[mi][kb] = ap[kb * 4];                // stride 32 bf16 = 4 chunks
    }

    f32x4 acc[2][8];
    #pragma unroll
    for (int mi = 0; mi < 2; ++mi)
        #pragma unroll
        for (int fn = 0; fn < 8; ++fn)
            #pragma unroll
            for (int c = 0; c < 4; ++c) acc[mi][fn][c] = 0.f;

    #pragma unroll
    for (int kb = 0; kb < 4; ++kb) {
        bf16x8 b[8];
        #pragma unroll
        for (int fn = 0; fn < 8; ++fn)
            b[fn] = *reinterpret_cast<const bf16x8*>(
                        &wb[((size_t)(kb * 8 + fn) * 64 + lane) * 8]);
        #pragma unroll
        for (int mi = 0; mi < 2; ++mi) {
            #pragma unroll
            for (int fn = 0; fn < 8; ++fn)
                acc[mi][fn] = __builtin_amdgcn_mfma_f32_16x16x32_bf16(
                                  av[mi][kb], b[fn], acc[mi][fn], 0, 0, 0);
        }
    }

    // C/D layout: col = lane&15 (+fn*16), row = (lane>>4)*4 + r (+mi*16)
    #pragma unroll
    for (int mi = 0; mi < 2; ++mi)
        #pragma unroll
        for (int r = 0; r < 4; ++r) {
            int row = row_base + mi * 16 + l4 * 4 + r;
            if (row >= M) continue;
            #pragma unroll
            for (int fn = 0; fn < 8; ++fn)
                y[(size_t)row * D + fn * 16 + l15] = f2bf(acc[mi][fn][r]);
        }
}

// ---------------------------------------------------------------------------
// Gather-sum from bf16 y: one wave per node, 8 edges in flight (pad8 bins),
// per-edge values SCALARIZED via readfirstlane (wave-uniform) -> y-loads use
// SGPR-base + lane-offset addressing, minimal VALU in the hot loop.
// ---------------------------------------------------------------------------
__global__ __launch_bounds__(256) void gather_kernel(
    const __bf16* __restrict__ y, const int* __restrict__ base,
    const int2* __restrict__ bins, const float* __restrict__ bias,
    float* __restrict__ out, int N)
{
    int gw   = (blockIdx.x * 256 + threadIdx.x) >> 6;
    int lane = threadIdx.x & 63;
    if (gw >= N) return;

    const unsigned* yb = reinterpret_cast<const unsigned*>(y);  // 2 bf16 / uint
    const int b0 = __builtin_amdgcn_readfirstlane(base[gw]);
    const int b1 = __builtin_amdgcn_readfirstlane(base[gw + 1]);
    float accx = 0.f, accy = 0.f;

    for (int i = b0; i < b1; i += 8) {
        int   rx[8];
        float w[8];
        #pragma unroll
        for (int t = 0; t < 8; ++t) {
            int2 ev = bins[i + t];                          // wave-uniform
            rx[t] = __builtin_amdgcn_readfirstlane(ev.x);   // row offset (SGPR)
            w[t]  = __int_as_float(__builtin_amdgcn_readfirstlane(ev.y));
        }
        unsigned p[8];
        #pragma unroll
        for (int t = 0; t < 8; ++t)
            p[t] = yb[(unsigned)rx[t] + lane];              // saddr + voffset
        #pragma unroll
        for (int t = 0; t < 8; ++t) {
            accx += __uint_as_float(p[t] << 16) * w[t];
            accy += __uint_as_float(p[t] & 0xFFFF0000u) * w[t];
        }
    }

    float2 bv = *reinterpret_cast<const float2*>(&bias[lane * 2]);
    f32x2 o;
    o[0] = accx + bv.x;
    o[1] = accy + bv.y;
    __builtin_nontemporal_store(o, reinterpret_cast<f32x2*>(&out[(size_t)gw * D + lane * 2]));
}

extern "C" void kernel_launch(void* const* d_in, const int* in_sizes, int n_in,
                              void* d_out, int out_size, void* d_ws, size_t ws_size,
                              hipStream_t stream) {
    const float* x   = (const float*)d_in[0];
    const float* ew  = (const float*)d_in[1];
    const int*   src = (const int*)d_in[2];
    const int*   dst = (const int*)d_in[3];
    const float* W   = (const float*)d_in[4];
    const float* b   = (const float*)d_in[5];
    float*       out = (float*)d_out;

    const int E  = in_sizes[2];                 // 640000
    const int M  = out_size / D;                // 100000 nodes
    const int NB = (M + SCAN_CH - 1) / SCAN_CH; // 25 (<=64 required)
    const size_t BIN_CAP = ((size_t)E + 7 * (size_t)M + 8) & ~(size_t)1;
    const long   N8      = (long)M * D / 8;     // 1.6M bf16x8 chunks

    // ws layout: y bf16[M*D] | xb bf16[M*D] | wb bf16[32*64*8] |
    //            bins int2[BIN_CAP] | base[M+1] | cnt[M] | rank[E] | bsum[NB]
    char* p = (char*)d_ws;
    __bf16* y    = (__bf16*)p;             p += (size_t)M * D * 2;
    __bf16* xb   = (__bf16*)p;             p += (size_t)M * D * 2;
    __bf16* wb   = (__bf16*)p;             p += (size_t)32 * 64 * 8 * 2;
    int2*   bins = (int2*)p;               p += BIN_CAP * 8;
    int*    base = (int*)p;                p += (size_t)(M + 1) * 4;
    int*    cnt  = (int*)p;                p += (size_t)M * 4;
    int*    rank = (int*)p;                p += (size_t)E * 4;
    int*    bsum = (int*)p;

    // 1) zero cnt + pack W (small)
    prep_kernel<<<512, 256, 0, stream>>>(W, wb, cnt, M);

    // 2) parity-interleaved: hist (odd blocks) || conv+zero-bins (even blocks)
    int histBlocks = (E + 255) / 256;           // 2500
    convhist_kernel<<<2 * histBlocks, 256, 0, stream>>>(
        x, xb, N8, (int4*)bins, (long)(BIN_CAP / 2), dst, cnt, rank, E, histBlocks);

    // 3-4) scan over padded counts (pad8)
    scan_part_kernel<<<NB, 256, 0, stream>>>(cnt, bsum, M);
    scan_write_kernel<<<NB, 256, 0, stream>>>(cnt, bsum, base, M, NB);

    // 5) fused: bf16-A GEMM (hoisted A-loads) blocks first, bin blocks trail
    int gemmBlocks = (M + 127) / 128;           // 782
    int binBlocks  = (E + 255) / 256;           // 2500
    bingemm_kernel<<<gemmBlocks + binBlocks, 256, 0, stream>>>(
        xb, wb, y, M, gemmBlocks, src, dst, ew, base, rank, bins, E);

    // 6) out[n] = sum_{e in node n} y[src_e] * w_e + bias
    gather_kernel<<<(M * 64 + 255) / 256, 256, 0, stream>>>(y, base, bins, b, out, M);
}